// Round 12
// baseline (14.624 us; speedup 1.0000x reference)
//
#include <hip/hip_runtime.h>

#define DIM    128
#define LAYERS 8
#define NQ     7
#define WPB    4

// Buffer PROVEN f32 (rounds 10/11). Circuit core PROVEN on-HW (round 4).
// Valid layout tests so far: interleaved f32 FAILED (r1).
// THIS ROUND: planar-global f32 = np.stack([z.real, z.imag], axis=0).
__device__ __forceinline__ int perm_g (int x) { x ^= x >> 1; x ^= x >> 2; x ^= x >> 4; return x; }
__device__ __forceinline__ int perm_gi(int x) { return x ^ (x >> 1); }

__device__ __forceinline__ float2 cmul2(float2 m0, float2 a, float2 m1, float2 b) {
    float2 r;
    r.x = m0.x * a.x - m0.y * a.y + m1.x * b.x - m1.y * b.y;
    r.y = m0.x * a.y + m0.y * a.x + m1.x * b.y + m1.y * b.x;
    return r;
}

__global__ __launch_bounds__(64 * WPB) void qsim_kernel(
        const float* __restrict__ state,          // (TB, 128) f32
        const float* __restrict__ params,         // (TB, 8, 7, 3) f32
        float* __restrict__ out,                  // f32: [TB*128 re | TB*128 im]
        int TB) {
    __shared__ float4 gm[WPB][LAYERS * NQ][2];

    const int wv = threadIdx.x >> 6;
    const int L  = threadIdx.x & 63;
    const int bb = blockIdx.x * WPB + wv;
    const bool active = (bb < TB);

    if (active && L < LAYERS * NQ) {
        const float* pp = params + (size_t)bb * (LAYERS * NQ * 3) + L * 3;
        const float omega = pp[0], theta = pp[1], phi = pp[2];
        float sa, ca; sincosf(0.5f * (phi + omega), &sa, &ca);  // e1=(ca,-sa)
        float sb, cb; sincosf(0.5f * (phi - omega), &sb, &cb);  // e2=(cb, sb)
        float st, ct; sincosf(0.5f * theta,         &st, &ct);
        gm[wv][L][0] = make_float4(ca * ct, -sa * ct, -cb * st, -sb * st); // m00,m01
        gm[wv][L][1] = make_float4(cb * st, -sb * st,  ca * ct,  sa * ct); // m10,m11
    }
    __syncthreads();
    if (!active) return;

    float2 lo = make_float2(state[bb * DIM + L],      0.0f);
    float2 hi = make_float2(state[bb * DIM + L + 64], 0.0f);

    const int gL = perm_g (L),  gH = perm_g (L | 64) & 63;
    const int iL = perm_gi(L),  iH = perm_gi(L | 64) & 63;

    #pragma unroll
    for (int l = 0; l < LAYERS; ++l) {
        {   // q=0 (bit 6): pair lives in-lane
            const float4 r0 = gm[wv][l * NQ][0];
            const float4 r1 = gm[wv][l * NQ][1];
            const float2 nlo = cmul2(make_float2(r0.x, r0.y), lo, make_float2(r0.z, r0.w), hi);
            const float2 nhi = cmul2(make_float2(r1.x, r1.y), lo, make_float2(r1.z, r1.w), hi);
            lo = nlo; hi = nhi;
        }
        #pragma unroll
        for (int q = 1; q < NQ; ++q) {   // shuffle butterflies in each 64-half
            const int m   = 64 >> q;
            const int bit = L & m;
            const float4 r = gm[wv][l * NQ + q][bit ? 1 : 0];
            const float2 m0 = make_float2(r.x, r.y), m1 = make_float2(r.z, r.w);
            float2 plo, phl;
            plo.x = __shfl_xor(lo.x, m); plo.y = __shfl_xor(lo.y, m);
            phl.x = __shfl_xor(hi.x, m); phl.y = __shfl_xor(hi.y, m);
            const float2 a_lo = bit ? plo : lo,  b_lo = bit ? lo : plo;
            const float2 a_hi = bit ? phl : hi,  b_hi = bit ? hi : phl;
            lo = cmul2(m0, a_lo, m1, b_lo);
            hi = cmul2(m0, a_hi, m1, b_hi);
        }
        // entangler: E (even l) / E^T (odd l)
        const int sl = (l & 1) ? iL : gL;
        const int sh = (l & 1) ? iH : gH;
        float2 nlo, nhi;
        nlo.x = __shfl(lo.x, sl); nlo.y = __shfl(lo.y, sl);
        nhi.x = __shfl(hi.x, sh); nhi.y = __shfl(hi.y, sh);
        lo = nlo; hi = nhi;
    }

    // --- PLANAR-GLOBAL f32 store: [all re | all im] ---
    const size_t TOT = (size_t)TB * DIM;
    const size_t e   = (size_t)bb * DIM + L;
    out[e]            = lo.x;   // re, x = L
    out[e + 64]       = hi.x;   // re, x = L+64
    out[TOT + e]      = lo.y;   // im, x = L
    out[TOT + e + 64] = hi.y;   // im, x = L+64
}

extern "C" void kernel_launch(void* const* d_in, const int* in_sizes, int n_in,
                              void* d_out, int out_size, void* d_ws, size_t ws_size,
                              hipStream_t stream) {
    // d_in[0]=state (TB*128), d_in[1]=params (TB*168); size-disambiguated safety net.
    const float* input_state;
    const float* params;
    int TB;
    if (in_sizes[0] < in_sizes[1]) {
        input_state = (const float*)d_in[0];
        params      = (const float*)d_in[1];
        TB = in_sizes[0] / DIM;
    } else {
        params      = (const float*)d_in[0];
        input_state = (const float*)d_in[1];
        TB = in_sizes[1] / DIM;
    }
    float* out = (float*)d_out;   // f32 buffer (proven r10/r11)

    const int grid = (TB + WPB - 1) / WPB;
    qsim_kernel<<<grid, 64 * WPB, 0, stream>>>(input_state, params, out, TB);
}

// Round 13
// 10.743 us; speedup vs baseline: 1.3613x; 1.3613x over previous
//
#include <hip/hip_runtime.h>

#define DIM    128
#define LAYERS 8
#define NQ     7

// (E s)[x] = s[perm_g(x)] ; (E^T s)[x] = s[perm_gi(x)]  — proven on-HW (r4).
__device__ __forceinline__ int perm_g (int x) { x ^= x >> 1; x ^= x >> 2; x ^= x >> 4; return x; }
__device__ __forceinline__ int perm_gi(int x) { return x ^ (x >> 1); }

// Fast xor-shuffle: DPP quad_perm for masks 1,2; ds_swizzle bitmode for 4,8,16
// (offset = xor_mask<<10 | 0x1F per ISA doc); __shfl_xor for 32.
template<int M>
__device__ __forceinline__ float shfx(float x) {
    int v = __float_as_int(x); int r;
    if constexpr (M == 1)       r = __builtin_amdgcn_update_dpp(0, v, 0xB1, 0xF, 0xF, true); // [1,0,3,2]
    else if constexpr (M == 2)  r = __builtin_amdgcn_update_dpp(0, v, 0x4E, 0xF, 0xF, true); // [2,3,0,1]
    else if constexpr (M == 4)  r = __builtin_amdgcn_ds_swizzle(v, 0x101F);
    else if constexpr (M == 8)  r = __builtin_amdgcn_ds_swizzle(v, 0x201F);
    else if constexpr (M == 16) r = __builtin_amdgcn_ds_swizzle(v, 0x401F);
    else                        r = __shfl_xor(v, 32);
    return __int_as_float(r);
}

// r = m0*a + m1*b  (complex)
__device__ __forceinline__ float2 cmul2(float2 m0, float2 a, float2 m1, float2 b) {
    float2 r;
    r.x = m0.x * a.x - m0.y * a.y + m1.x * b.x - m1.y * b.y;
    r.y = m0.x * a.y + m0.y * a.x + m1.x * b.y + m1.y * b.x;
    return r;
}

template<int M>
__device__ __forceinline__ void butterfly(int L, float2& lo, float2& hi, float4 g) {
    const int bit = L & M;
    const float2 m0 = make_float2(g.x, g.y), m1 = make_float2(g.z, g.w);
    float2 plo, phl;
    plo.x = shfx<M>(lo.x); plo.y = shfx<M>(lo.y);
    phl.x = shfx<M>(hi.x); phl.y = shfx<M>(hi.y);
    const float2 a_lo = bit ? plo : lo,  b_lo = bit ? lo : plo;
    const float2 a_hi = bit ? phl : hi,  b_hi = bit ? hi : phl;
    lo = cmul2(m0, a_lo, m1, b_lo);
    hi = cmul2(m0, a_hi, m1, b_hi);
}

__global__ __launch_bounds__(64) void qsim_kernel(
        const float* __restrict__ state,          // (TB, 128) f32
        const float* __restrict__ params,         // (TB, 8, 7, 3) f32
        float* __restrict__ out,                  // f32 planar: [TB*128 re | TB*128 im]
        int TB) {
    __shared__ float4 gm[LAYERS * NQ][2];         // one wave per block

    const int L  = threadIdx.x;
    const int bb = blockIdx.x;

    // Hoist state loads to the very top: latency overlaps gate build + barrier.
    float2 lo = make_float2(state[bb * DIM + L],      0.0f);
    float2 hi = make_float2(state[bb * DIM + L + 64], 0.0f);

    // --- 56 gate matrices: lanes 0..55, native trig (|args| < ~7, err ~1e-5) ---
    if (L < LAYERS * NQ) {
        const float* pp = params + (size_t)bb * (LAYERS * NQ * 3) + L * 3;
        const float omega = pp[0], theta = pp[1], phi = pp[2];
        const float a = 0.5f * (phi + omega), b = 0.5f * (phi - omega), t = 0.5f * theta;
        const float sa = __sinf(a), ca = __cosf(a);   // e1 = (ca,-sa)
        const float sb = __sinf(b), cb = __cosf(b);   // e2 = (cb, sb)
        const float st = __sinf(t), ct = __cosf(t);
        gm[L][0] = make_float4(ca * ct, -sa * ct, -cb * st, -sb * st); // m00,m01
        gm[L][1] = make_float4(cb * st, -sb * st,  ca * ct,  sa * ct); // m10,m11
    }
    __syncthreads();   // single-wave workgroup: compiles to a waitcnt, no skew

    const int gL = perm_g (L),  gH = perm_g (L | 64) & 63;
    const int iL = perm_gi(L),  iH = perm_gi(L | 64) & 63;

    #pragma unroll
    for (int l = 0; l < LAYERS; ++l) {
        const int base = l * NQ;
        // Per-layer register preload of this lane's gate rows: off the round path.
        const float4 G0a = gm[base + 0][0];
        const float4 G0b = gm[base + 0][1];
        const float4 G1  = gm[base + 1][(L >> 5) & 1];
        const float4 G2  = gm[base + 2][(L >> 4) & 1];
        const float4 G3  = gm[base + 3][(L >> 3) & 1];
        const float4 G4  = gm[base + 4][(L >> 2) & 1];
        const float4 G5  = gm[base + 5][(L >> 1) & 1];
        const float4 G6  = gm[base + 6][L & 1];

        // q=0 (bit 6): pair lives in-lane
        {
            const float2 nlo = cmul2(make_float2(G0a.x, G0a.y), lo, make_float2(G0a.z, G0a.w), hi);
            const float2 nhi = cmul2(make_float2(G0b.x, G0b.y), lo, make_float2(G0b.z, G0b.w), hi);
            lo = nlo; hi = nhi;
        }
        butterfly<32>(L, lo, hi, G1);
        butterfly<16>(L, lo, hi, G2);
        butterfly< 8>(L, lo, hi, G3);
        butterfly< 4>(L, lo, hi, G4);
        butterfly< 2>(L, lo, hi, G5);
        butterfly< 1>(L, lo, hi, G6);

        // entangler: E (even l) / E^T (odd l) — lane gather per half
        const int sl = (l & 1) ? iL : gL;
        const int sh = (l & 1) ? iH : gH;
        float2 nlo, nhi;
        nlo.x = __shfl(lo.x, sl); nlo.y = __shfl(lo.y, sl);
        nhi.x = __shfl(hi.x, sh); nhi.y = __shfl(hi.y, sh);
        lo = nlo; hi = nhi;
    }

    // --- planar-global f32 store (validated layout): [all re | all im] ---
    const size_t TOT = (size_t)TB * DIM;
    const size_t e   = (size_t)bb * DIM + L;
    out[e]            = lo.x;
    out[e + 64]       = hi.x;
    out[TOT + e]      = lo.y;
    out[TOT + e + 64] = hi.y;
}

extern "C" void kernel_launch(void* const* d_in, const int* in_sizes, int n_in,
                              void* d_out, int out_size, void* d_ws, size_t ws_size,
                              hipStream_t stream) {
    // d_in[0]=state (TB*128), d_in[1]=params (TB*168); size-disambiguated safety net.
    const float* input_state;
    const float* params;
    int TB;
    if (in_sizes[0] < in_sizes[1]) {
        input_state = (const float*)d_in[0];
        params      = (const float*)d_in[1];
        TB = in_sizes[0] / DIM;
    } else {
        params      = (const float*)d_in[0];
        input_state = (const float*)d_in[1];
        TB = in_sizes[1] / DIM;
    }
    float* out = (float*)d_out;   // f32 buffer (proven r10/r11)

    qsim_kernel<<<TB, 64, 0, stream>>>(input_state, params, out, TB);
}

// Round 14
// 10.520 us; speedup vs baseline: 1.3900x; 1.0211x over previous
//
#include <hip/hip_runtime.h>

#define DIM    128
#define LAYERS 8
#define NQ     7

// (E s)[x] = s[perm_g(x)] ; (E^T s)[x] = s[perm_gi(x)]  — proven on-HW (r4).
__device__ __forceinline__ int perm_g (int x) { x ^= x >> 1; x ^= x >> 2; x ^= x >> 4; return x; }
__device__ __forceinline__ int perm_gi(int x) { return x ^ (x >> 1); }

// XOR-shuffles:
//  M=1 : DPP quad_perm [1,0,3,2]               (VALU)
//  M=2 : DPP quad_perm [2,3,0,1]               (VALU)
//  M=4 : DPP quad_perm [3,2,1,0] (l^3) then row_half_mirror (l^7 in 8) -> l^4 (VALU)
//  M=8 : DPP row_ror:8  ((l+-8)%16 == l^8, direction-proof)            (VALU)
//  M=16: ds_swizzle bitmode xor16 (0x401F)                             (LDS)
//  M=32: __shfl_xor 32                                                 (LDS)
template<int M>
__device__ __forceinline__ float shfx(float x) {
    int v = __float_as_int(x); int r;
    if constexpr (M == 1)       r = __builtin_amdgcn_update_dpp(0, v, 0xB1, 0xF, 0xF, true);
    else if constexpr (M == 2)  r = __builtin_amdgcn_update_dpp(0, v, 0x4E, 0xF, 0xF, true);
    else if constexpr (M == 4) {
        int t = __builtin_amdgcn_update_dpp(0, v, 0x1B, 0xF, 0xF, true);   // l^3
        r = __builtin_amdgcn_update_dpp(0, t, 0x141, 0xF, 0xF, true);      // ^7 -> l^4
    }
    else if constexpr (M == 8)  r = __builtin_amdgcn_update_dpp(0, v, 0x128, 0xF, 0xF, true); // row_ror:8
    else if constexpr (M == 16) r = __builtin_amdgcn_ds_swizzle(v, 0x401F);
    else                        r = __shfl_xor(v, 32);
    return __int_as_float(r);
}

// r = m0*a + m1*b  (complex)
__device__ __forceinline__ float2 cmul2(float2 m0, float2 a, float2 m1, float2 b) {
    float2 r;
    r.x = m0.x * a.x - m0.y * a.y + m1.x * b.x - m1.y * b.y;
    r.y = m0.x * a.y + m0.y * a.x + m1.x * b.y + m1.y * b.x;
    return r;
}

template<int M>
__device__ __forceinline__ void butterfly(int L, float2& lo, float2& hi, float4 g) {
    const int bit = L & M;
    const float2 m0 = make_float2(g.x, g.y), m1 = make_float2(g.z, g.w);
    float2 plo, phl;
    plo.x = shfx<M>(lo.x); plo.y = shfx<M>(lo.y);
    phl.x = shfx<M>(hi.x); phl.y = shfx<M>(hi.y);
    const float2 a_lo = bit ? plo : lo,  b_lo = bit ? lo : plo;
    const float2 a_hi = bit ? phl : hi,  b_hi = bit ? hi : phl;
    lo = cmul2(m0, a_lo, m1, b_lo);
    hi = cmul2(m0, a_hi, m1, b_hi);
}

__global__ __launch_bounds__(64) void qsim_kernel(
        const float* __restrict__ state,          // (TB, 128) f32
        const float* __restrict__ params,         // (TB, 8, 7, 3) f32
        float* __restrict__ out,                  // f32 planar: [TB*128 re | TB*128 im]
        int TB) {
    __shared__ float4 gm[LAYERS * NQ][2];         // one wave per block

    const int L  = threadIdx.x;
    const int bb = blockIdx.x;

    // Hoist state loads: latency overlaps gate build.
    float2 lo = make_float2(state[bb * DIM + L],      0.0f);
    float2 hi = make_float2(state[bb * DIM + L + 64], 0.0f);

    // --- 56 gate matrices: lanes 0..55, native trig (|args| < ~7, err ~1e-5) ---
    if (L < LAYERS * NQ) {
        const float* pp = params + (size_t)bb * (LAYERS * NQ * 3) + L * 3;
        const float omega = pp[0], theta = pp[1], phi = pp[2];
        const float a = 0.5f * (phi + omega), b = 0.5f * (phi - omega), t = 0.5f * theta;
        const float sa = __sinf(a), ca = __cosf(a);   // e1 = (ca,-sa)
        const float sb = __sinf(b), cb = __cosf(b);   // e2 = (cb, sb)
        const float st = __sinf(t), ct = __cosf(t);
        gm[L][0] = make_float4(ca * ct, -sa * ct, -cb * st, -sb * st); // m00,m01
        gm[L][1] = make_float4(cb * st, -sb * st,  ca * ct,  sa * ct); // m10,m11
    }
    __syncthreads();   // single-wave workgroup: cheap

    const int gL = perm_g (L),  gH = perm_g (L | 64) & 63;
    const int iL = perm_gi(L),  iH = perm_gi(L | 64) & 63;

    #pragma unroll
    for (int l = 0; l < LAYERS; ++l) {
        const int base = l * NQ;
        // Register preload of this lane's gate rows (off the round-critical path).
        const float4 G0a = gm[base + 0][0];
        const float4 G0b = gm[base + 0][1];
        const float4 G1  = gm[base + 1][(L >> 5) & 1];
        const float4 G2  = gm[base + 2][(L >> 4) & 1];
        const float4 G3  = gm[base + 3][(L >> 3) & 1];
        const float4 G4  = gm[base + 4][(L >> 2) & 1];
        const float4 G5  = gm[base + 5][(L >> 1) & 1];
        const float4 G6  = gm[base + 6][L & 1];

        // q=0 (bit 6): pair lives in-lane
        {
            const float2 nlo = cmul2(make_float2(G0a.x, G0a.y), lo, make_float2(G0a.z, G0a.w), hi);
            const float2 nhi = cmul2(make_float2(G0b.x, G0b.y), lo, make_float2(G0b.z, G0b.w), hi);
            lo = nlo; hi = nhi;
        }
        butterfly<32>(L, lo, hi, G1);   // LDS
        butterfly<16>(L, lo, hi, G2);   // LDS
        butterfly< 8>(L, lo, hi, G3);   // DPP
        butterfly< 4>(L, lo, hi, G4);   // DPP x2
        butterfly< 2>(L, lo, hi, G5);   // DPP
        butterfly< 1>(L, lo, hi, G6);   // DPP

        // entangler: E (even l) / E^T (odd l) — lane gather per half (LDS)
        const int sl = (l & 1) ? iL : gL;
        const int sh = (l & 1) ? iH : gH;
        float2 nlo, nhi;
        nlo.x = __shfl(lo.x, sl); nlo.y = __shfl(lo.y, sl);
        nhi.x = __shfl(hi.x, sh); nhi.y = __shfl(hi.y, sh);
        lo = nlo; hi = nhi;
    }

    // --- planar-global f32 store (validated layout): [all re | all im] ---
    const size_t TOT = (size_t)TB * DIM;
    const size_t e   = (size_t)bb * DIM + L;
    out[e]            = lo.x;
    out[e + 64]       = hi.x;
    out[TOT + e]      = lo.y;
    out[TOT + e + 64] = hi.y;
}

extern "C" void kernel_launch(void* const* d_in, const int* in_sizes, int n_in,
                              void* d_out, int out_size, void* d_ws, size_t ws_size,
                              hipStream_t stream) {
    // d_in[0]=state (TB*128), d_in[1]=params (TB*168); size-disambiguated safety net.
    const float* input_state;
    const float* params;
    int TB;
    if (in_sizes[0] < in_sizes[1]) {
        input_state = (const float*)d_in[0];
        params      = (const float*)d_in[1];
        TB = in_sizes[0] / DIM;
    } else {
        params      = (const float*)d_in[0];
        input_state = (const float*)d_in[1];
        TB = in_sizes[1] / DIM;
    }
    float* out = (float*)d_out;   // f32 buffer (proven r10/r11)

    qsim_kernel<<<TB, 64, 0, stream>>>(input_state, params, out, TB);
}